// Round 12
// baseline (942.694 us; speedup 1.0000x reference)
//
#include <hip/hip_runtime.h>
#include <hip/hip_bf16.h>

// ParallelExperts: per-expert LayerNorm -> Linear(1024->4096) -> tanh-GELU
// E=16 experts, 512 tokens each (balanced), fp32 in/out, bf16 MFMA inside.

#define E_EXP 16
#define T_TOK 8192
#define DIN   1024
#define DOUT  4096

typedef __bf16 bf16;
typedef __bf16 bf16x4v __attribute__((ext_vector_type(4)));
typedef __bf16 bf16x8v __attribute__((ext_vector_type(8)));
typedef float  f32x4   __attribute__((ext_vector_type(4)));

typedef __attribute__((address_space(1))) void gvoid;
typedef __attribute__((address_space(3))) void lvoid;

#define SCHED_FENCE __builtin_amdgcn_sched_barrier(0)

// ---------------- LayerNorm -> bf16 (one block per token) ----------------
__global__ __launch_bounds__(256) void ln_bf16_kernel(
    const float* __restrict__ x, const float* __restrict__ gamma,
    const float* __restrict__ beta, bf16* __restrict__ xn) {
  const int t    = blockIdx.x;
  const int e    = t >> 9;            // 512 tokens per expert
  const int tid  = threadIdx.x;
  const float4 xv = reinterpret_cast<const float4*>(x + (size_t)t * DIN)[tid];
  float s  = xv.x + xv.y + xv.z + xv.w;
  float s2 = xv.x * xv.x + xv.y * xv.y + xv.z * xv.z + xv.w * xv.w;
#pragma unroll
  for (int o = 32; o > 0; o >>= 1) {
    s  += __shfl_xor(s,  o, 64);
    s2 += __shfl_xor(s2, o, 64);
  }
  __shared__ float red[8];
  const int lane = tid & 63, wid = tid >> 6;
  if (lane == 0) { red[wid] = s; red[4 + wid] = s2; }
  __syncthreads();
  s  = red[0] + red[1] + red[2] + red[3];
  s2 = red[4] + red[5] + red[6] + red[7];
  const float mu  = s * (1.0f / DIN);
  const float var = s2 * (1.0f / DIN) - mu * mu;
  const float inv = rsqrtf(var + 1e-5f);
  const float4 g = reinterpret_cast<const float4*>(gamma + (size_t)e * DIN)[tid];
  const float4 b = reinterpret_cast<const float4*>(beta  + (size_t)e * DIN)[tid];
  bf16x4v o;
  o[0] = (bf16)((xv.x - mu) * inv * g.x + b.x);
  o[1] = (bf16)((xv.y - mu) * inv * g.y + b.y);
  o[2] = (bf16)((xv.z - mu) * inv * g.z + b.z);
  o[3] = (bf16)((xv.w - mu) * inv * g.w + b.w);
  *reinterpret_cast<bf16x4v*>(xn + (size_t)t * DIN + tid * 4) = o;
}

// ---------------- grouped GEMM: C = GELU(xn @ W[e] + b[e]) ----------------
// 128m x 256n tile, BK=32, FOUR waves (1m x 4n), per-wave 128x64 output.
// 4-wave blocks + 252 regs/wave -> 3 waves/SIMD -> THREE blocks/CU: barrier
// stalls of one block are filled by the other two blocks' MFMA (the TLP that
// 8-wave/1-block-per-CU rounds R5-R11 never had).
// B never touches LDS: per-wave register gather from W fp32 (32 dwords,
// 4x64B segments/inst) + in-register cvt. A staged via source-swizzled
// global_load_lds, triple-buffered at distance 2. One barrier per K-step,
// no waitcnt asm: CVT_B's register dependency is the counted drain
// (drains B(kt)+A(kt), leaves A(kt+1)+B(kt+1) in flight).
#define BM 128
#define BN 256
#define BK 32
#define NK (DIN / BK)   // 32 K-steps

__global__ __launch_bounds__(256, 3) void grouped_gemm_kernel(
    const bf16* __restrict__ xn, const float* __restrict__ W,
    const float* __restrict__ bias, float* __restrict__ out) {
  __shared__ bf16 Alds[3][BM * BK];   // 3 x 8 KB (A only)

  const int tid    = threadIdx.x;
  const int lane   = tid & 63;
  const int wid    = tid >> 6;       // 0..3
  const int warp_n = wid;            // 0..3 (n-quadrant); all waves share m
  const int q      = lane >> 4;      // 0..3 (k-octet of this lane)
  const int lp     = lane & 15;
  const int sw     = (lp >> 1) & 3;  // A frag-read XOR slot

  // XCD swizzle: 1024 blocks, 8 XCDs, 128 contiguous per XCD.
  // XCD x covers mtiles [x*8, x*8+8) (= 2 experts) x all 16 ntiles;
  // within an XCD, the 8 same-ntile blocks are consecutive -> their 2 W
  // slices (2 MB) + 8 A panels (2 MB) are L2-resident.
  const int xcd    = blockIdx.x & 7;
  const int s      = blockIdx.x >> 3;      // 0..127
  const int ntile  = s >> 3;               // 0..15
  const int mtile  = xcd * 8 + (s & 7);    // 0..63
  const int e      = mtile >> 2;           // 4 m-tiles per expert
  const int t0     = mtile * BM;
  const int n0     = ntile * BN;

  f32x4 acc[8][4];
#pragma unroll
  for (int i = 0; i < 8; ++i)
#pragma unroll
    for (int j = 0; j < 4; ++j)
      acc[i][j] = (f32x4){0.f, 0.f, 0.f, 0.f};

  const bf16*  Abase = xn + (size_t)t0 * DIN;
  const float* Wexp  = W + (size_t)e * DIN * DOUT + n0;

  // A staging source group (pre-swizzle so linear LDS dest ends up with
  // phys_grp = log_grp ^ ((row>>1)&3); row-within-inst = lane>>2).
  const int akg  = (lane & 3) ^ ((lane >> 3) & 3);
  const int nofs = warp_n * 64 + lp;   // this lane's base n within the panel

  float gB[32];   // B gather registers (tile kt+1 in flight during MFMA kt)

#define STAGE_A(buf, k0)                                                      \
  {                                                                           \
    _Pragma("unroll")                                                         \
    for (int c = 0; c < 2; ++c) {                                             \
      const int ci = wid * 2 + c;                  /* 0..7, 16 rows each */   \
      const bf16* g = Abase + (size_t)(ci * 16 + (lane >> 2)) * DIN + (k0) +  \
                      akg * 8;                                                \
      __builtin_amdgcn_global_load_lds((gvoid*)g,                             \
                                       (lvoid*)&Alds[buf][ci * 512], 16, 0, 0); \
    }                                                                         \
  }

// Per-wave B gather: element (ni,j) = W[k0+q*8+j][n0+nofs+ni*16].
// Lanes of one inst: 4 q-groups x 16 consecutive n -> 4x64B segments.
#define GATHER_B(k0)                                                          \
  {                                                                           \
    _Pragma("unroll")                                                         \
    for (int j = 0; j < 8; ++j) {                                             \
      const float* wr = Wexp + (size_t)((k0) + q * 8 + j) * DOUT + nofs;      \
      _Pragma("unroll")                                                       \
      for (int ni = 0; ni < 4; ++ni) gB[ni * 8 + j] = wr[ni * 16];            \
    }                                                                         \
  }

#define CVT_B                                                                 \
  {                                                                           \
    _Pragma("unroll")                                                         \
    for (int ni = 0; ni < 4; ++ni)                                            \
      _Pragma("unroll")                                                       \
      for (int j = 0; j < 8; ++j) bfr[ni][j] = (bf16)gB[ni * 8 + j];          \
  }

#define RD_A(AB)                                                              \
  {                                                                           \
    _Pragma("unroll")                                                         \
    for (int mi = 0; mi < 8; ++mi)                                            \
      af[mi] = *reinterpret_cast<const bf16x8v*>(                             \
          &Alds[AB][(lp + mi * 16) * BK + ((q ^ sw) * 8)]);                   \
  }

#define MFMA_ALL                                                              \
  {                                                                           \
    _Pragma("unroll")                                                         \
    for (int mi = 0; mi < 8; ++mi)                                            \
      _Pragma("unroll")                                                       \
      for (int ni = 0; ni < 4; ++ni)                                          \
        acc[mi][ni] = __builtin_amdgcn_mfma_f32_16x16x32_bf16(                \
            af[mi], bfr[ni], acc[mi][ni], 0, 0, 0);                           \
  }

// One K-step. A0_ = current A buf (kt%3), AS_ = stage target ((kt+2)%3).
// STG: kt<30, LB: kt<31. CVT_B's register dependency drains B(kt)+A(kt)
// (FIFO-older) and leaves A(kt+1) + the new gathers in flight.
#define K_STEP(KT, A0_, AS_, STG, LB)                                         \
  {                                                                           \
    bf16x8v af[8], bfr[4];                                                    \
    CVT_B;                                                                    \
    SCHED_FENCE;                                                              \
    __builtin_amdgcn_s_barrier();                                             \
    SCHED_FENCE;                                                              \
    RD_A(A0_);                                                                \
    if (LB)  GATHER_B(((KT) + 1) * BK);                                       \
    if (STG) STAGE_A(AS_, ((KT) + 2) * BK);                                   \
    SCHED_FENCE;                                                              \
    __builtin_amdgcn_s_setprio(1); MFMA_ALL; __builtin_amdgcn_s_setprio(0);   \
  }

  // ---- prologue: issue order [A(0)] [B(0)] [A(1)] so step 0's cvt drains
  // B(0)+A(0) and leaves A(1) in flight (steady-state FIFO from step 0). ----
  STAGE_A(0, 0);
  SCHED_FENCE;
  GATHER_B(0);
  SCHED_FENCE;
  STAGE_A(1, BK);

  for (int kt = 0; kt < 30; kt += 3) {
    K_STEP(kt,     0, 2, 1, 1);
    K_STEP(kt + 1, 1, 0, 1, 1);
    K_STEP(kt + 2, 2, 1, 1, 1);
  }
  K_STEP(30, 0, 0, 0, 1);   // gathers B(31); A(31) already staged (kt=29)
  K_STEP(31, 1, 0, 0, 0);   // final K-step

  // --- epilogue: + bias, tanh-GELU (jax.nn.gelu approximate=True), fp32 out ---
  // gelu(v) = 0.5 v (1 + tanh(u)) = v / (1 + exp(-2u))
  const float* be = bias + (size_t)e * DOUT;
#pragma unroll
  for (int ni = 0; ni < 4; ++ni) {
    const int col = n0 + warp_n * 64 + ni * 16 + lp;
    const float bc = be[col];
#pragma unroll
    for (int mi = 0; mi < 8; ++mi) {
#pragma unroll
      for (int rr = 0; rr < 4; ++rr) {
        const int row = t0 + mi * 16 + q * 4 + rr;
        float v = acc[mi][ni][rr] + bc;
        const float u = 0.7978845608028654f * (v + 0.044715f * v * v * v);
        v = v / (1.0f + __expf(-2.0f * u));
        out[(size_t)row * DOUT + col] = v;
      }
    }
  }
}

extern "C" void kernel_launch(void* const* d_in, const int* in_sizes, int n_in,
                              void* d_out, int out_size, void* d_ws, size_t ws_size,
                              hipStream_t stream) {
  const float* x     = (const float*)d_in[0];
  // d_in[1] = expert_frequency: balanced by construction (512 each) -> unused
  const float* gamma = (const float*)d_in[2];
  const float* beta  = (const float*)d_in[3];
  const float* W     = (const float*)d_in[4];
  const float* bias  = (const float*)d_in[5];
  float* out = (float*)d_out;
  bf16* xn   = (bf16*)d_ws;    // 8192*1024 bf16 = 16 MiB scratch

  hipLaunchKernelGGL(ln_bf16_kernel, dim3(T_TOK), dim3(256), 0, stream,
                     x, gamma, beta, xn);
  hipLaunchKernelGGL(grouped_gemm_kernel, dim3((T_TOK / BM) * (DOUT / BN)),
                     dim3(256), 0, stream, xn, W, bias, out);
}

// Round 13
// 174.406 us; speedup vs baseline: 5.4052x; 5.4052x over previous
//
#include <hip/hip_runtime.h>
#include <hip/hip_bf16.h>

// ParallelExperts: per-expert LayerNorm -> Linear(1024->4096) -> tanh-GELU
// E=16 experts, 512 tokens each (balanced), fp32 in/out, bf16 MFMA inside.

#define E_EXP 16
#define T_TOK 8192
#define DIN   1024
#define DOUT  4096

typedef __bf16 bf16;
typedef __bf16 bf16x4v __attribute__((ext_vector_type(4)));
typedef __bf16 bf16x8v __attribute__((ext_vector_type(8)));
typedef float  f32x4   __attribute__((ext_vector_type(4)));

typedef __attribute__((address_space(1))) void gvoid;
typedef __attribute__((address_space(3))) void lvoid;

#define SCHED_FENCE __builtin_amdgcn_sched_barrier(0)

// ---------------- LayerNorm -> bf16 (one block per token) ----------------
__global__ __launch_bounds__(256) void ln_bf16_kernel(
    const float* __restrict__ x, const float* __restrict__ gamma,
    const float* __restrict__ beta, bf16* __restrict__ xn) {
  const int t    = blockIdx.x;
  const int e    = t >> 9;            // 512 tokens per expert
  const int tid  = threadIdx.x;
  const float4 xv = reinterpret_cast<const float4*>(x + (size_t)t * DIN)[tid];
  float s  = xv.x + xv.y + xv.z + xv.w;
  float s2 = xv.x * xv.x + xv.y * xv.y + xv.z * xv.z + xv.w * xv.w;
#pragma unroll
  for (int o = 32; o > 0; o >>= 1) {
    s  += __shfl_xor(s,  o, 64);
    s2 += __shfl_xor(s2, o, 64);
  }
  __shared__ float red[8];
  const int lane = tid & 63, wid = tid >> 6;
  if (lane == 0) { red[wid] = s; red[4 + wid] = s2; }
  __syncthreads();
  s  = red[0] + red[1] + red[2] + red[3];
  s2 = red[4] + red[5] + red[6] + red[7];
  const float mu  = s * (1.0f / DIN);
  const float var = s2 * (1.0f / DIN) - mu * mu;
  const float inv = rsqrtf(var + 1e-5f);
  const float4 g = reinterpret_cast<const float4*>(gamma + (size_t)e * DIN)[tid];
  const float4 b = reinterpret_cast<const float4*>(beta  + (size_t)e * DIN)[tid];
  bf16x4v o;
  o[0] = (bf16)((xv.x - mu) * inv * g.x + b.x);
  o[1] = (bf16)((xv.y - mu) * inv * g.y + b.y);
  o[2] = (bf16)((xv.z - mu) * inv * g.z + b.z);
  o[3] = (bf16)((xv.w - mu) * inv * g.w + b.w);
  *reinterpret_cast<bf16x4v*>(xn + (size_t)t * DIN + tid * 4) = o;
}

// ---------------- grouped GEMM: C = GELU(xn @ W[e] + b[e]) ----------------
// 128m x 256n tile, BK=32, FOUR waves (1m x 4n), per-wave 128x64 output.
// launch_bounds(256,2) -> 2 waves/SIMD (252 regs/wave fits the 512/SIMD
// pool) -> TWO independent 4-wave blocks per CU: one block's barrier/drain
// stalls overlap the other block's MFMA. (R12's ",3" forced 170 regs/wave
// -> spilled; the pool makes 3 waves/SIMD impossible at acc=128.)
// B never touches LDS: per-wave register gather from W fp32 (32 dwords,
// 4x64B segments/inst) + in-register cvt. A staged via source-swizzled
// global_load_lds, triple-buffered at distance 2. One barrier per K-step,
// no waitcnt asm: CVT_B's register dependency is the counted drain
// (drains B(kt)+A(kt), leaves A(kt+1)+B(kt+1) in flight).
#define BM 128
#define BN 256
#define BK 32
#define NK (DIN / BK)   // 32 K-steps

__global__ __launch_bounds__(256, 2) void grouped_gemm_kernel(
    const bf16* __restrict__ xn, const float* __restrict__ W,
    const float* __restrict__ bias, float* __restrict__ out) {
  __shared__ bf16 Alds[3][BM * BK];   // 3 x 8 KB (A only)

  const int tid    = threadIdx.x;
  const int lane   = tid & 63;
  const int wid    = tid >> 6;       // 0..3
  const int warp_n = wid;            // 0..3 (n-quadrant); all waves share m
  const int q      = lane >> 4;      // 0..3 (k-octet of this lane)
  const int lp     = lane & 15;
  const int sw     = (lp >> 1) & 3;  // A frag-read XOR slot

  // XCD swizzle: 1024 blocks, 8 XCDs, 128 contiguous per XCD.
  // XCD x covers mtiles [x*8, x*8+8) (= 2 experts) x all 16 ntiles;
  // within an XCD, the 8 same-ntile blocks are consecutive -> their 2 W
  // slices (2 MB) + 8 A panels (2 MB) are L2-resident.
  const int xcd    = blockIdx.x & 7;
  const int s      = blockIdx.x >> 3;      // 0..127
  const int ntile  = s >> 3;               // 0..15
  const int mtile  = xcd * 8 + (s & 7);    // 0..63
  const int e      = mtile >> 2;           // 4 m-tiles per expert
  const int t0     = mtile * BM;
  const int n0     = ntile * BN;

  f32x4 acc[8][4];
#pragma unroll
  for (int i = 0; i < 8; ++i)
#pragma unroll
    for (int j = 0; j < 4; ++j)
      acc[i][j] = (f32x4){0.f, 0.f, 0.f, 0.f};

  const bf16*  Abase = xn + (size_t)t0 * DIN;
  const float* Wexp  = W + (size_t)e * DIN * DOUT + n0;

  // A staging source group (pre-swizzle so linear LDS dest ends up with
  // phys_grp = log_grp ^ ((row>>1)&3); row-within-inst = lane>>2).
  const int akg  = (lane & 3) ^ ((lane >> 3) & 3);
  const int nofs = warp_n * 64 + lp;   // this lane's base n within the panel

  float gB[32];   // B gather registers (tile kt+1 in flight during MFMA kt)

#define STAGE_A(buf, k0)                                                      \
  {                                                                           \
    _Pragma("unroll")                                                         \
    for (int c = 0; c < 2; ++c) {                                             \
      const int ci = wid * 2 + c;                  /* 0..7, 16 rows each */   \
      const bf16* g = Abase + (size_t)(ci * 16 + (lane >> 2)) * DIN + (k0) +  \
                      akg * 8;                                                \
      __builtin_amdgcn_global_load_lds((gvoid*)g,                             \
                                       (lvoid*)&Alds[buf][ci * 512], 16, 0, 0); \
    }                                                                         \
  }

// Per-wave B gather: element (ni,j) = W[k0+q*8+j][n0+nofs+ni*16].
// Lanes of one inst: 4 q-groups x 16 consecutive n -> 4x64B segments.
#define GATHER_B(k0)                                                          \
  {                                                                           \
    _Pragma("unroll")                                                         \
    for (int j = 0; j < 8; ++j) {                                             \
      const float* wr = Wexp + (size_t)((k0) + q * 8 + j) * DOUT + nofs;      \
      _Pragma("unroll")                                                       \
      for (int ni = 0; ni < 4; ++ni) gB[ni * 8 + j] = wr[ni * 16];            \
    }                                                                         \
  }

#define CVT_B                                                                 \
  {                                                                           \
    _Pragma("unroll")                                                         \
    for (int ni = 0; ni < 4; ++ni)                                            \
      _Pragma("unroll")                                                       \
      for (int j = 0; j < 8; ++j) bfr[ni][j] = (bf16)gB[ni * 8 + j];          \
  }

#define RD_A(AB)                                                              \
  {                                                                           \
    _Pragma("unroll")                                                         \
    for (int mi = 0; mi < 8; ++mi)                                            \
      af[mi] = *reinterpret_cast<const bf16x8v*>(                             \
          &Alds[AB][(lp + mi * 16) * BK + ((q ^ sw) * 8)]);                   \
  }

#define MFMA_ALL                                                              \
  {                                                                           \
    _Pragma("unroll")                                                         \
    for (int mi = 0; mi < 8; ++mi)                                            \
      _Pragma("unroll")                                                       \
      for (int ni = 0; ni < 4; ++ni)                                          \
        acc[mi][ni] = __builtin_amdgcn_mfma_f32_16x16x32_bf16(                \
            af[mi], bfr[ni], acc[mi][ni], 0, 0, 0);                           \
  }

// One K-step. A0_ = current A buf (kt%3), AS_ = stage target ((kt+2)%3).
// STG: kt<30, LB: kt<31. CVT_B's register dependency drains B(kt)+A(kt)
// (FIFO-older) and leaves A(kt+1) + the new gathers in flight.
#define K_STEP(KT, A0_, AS_, STG, LB)                                         \
  {                                                                           \
    bf16x8v af[8], bfr[4];                                                    \
    CVT_B;                                                                    \
    SCHED_FENCE;                                                              \
    __builtin_amdgcn_s_barrier();                                             \
    SCHED_FENCE;                                                              \
    RD_A(A0_);                                                                \
    if (LB)  GATHER_B(((KT) + 1) * BK);                                       \
    if (STG) STAGE_A(AS_, ((KT) + 2) * BK);                                   \
    SCHED_FENCE;                                                              \
    __builtin_amdgcn_s_setprio(1); MFMA_ALL; __builtin_amdgcn_s_setprio(0);   \
  }

  // ---- prologue: issue order [A(0)] [B(0)] [A(1)] so step 0's cvt drains
  // B(0)+A(0) and leaves A(1) in flight (steady-state FIFO from step 0). ----
  STAGE_A(0, 0);
  SCHED_FENCE;
  GATHER_B(0);
  SCHED_FENCE;
  STAGE_A(1, BK);

  for (int kt = 0; kt < 30; kt += 3) {
    K_STEP(kt,     0, 2, 1, 1);
    K_STEP(kt + 1, 1, 0, 1, 1);
    K_STEP(kt + 2, 2, 1, 1, 1);
  }
  K_STEP(30, 0, 0, 0, 1);   // gathers B(31); A(31) already staged (kt=29)
  K_STEP(31, 1, 0, 0, 0);   // final K-step

  // --- epilogue: + bias, tanh-GELU (jax.nn.gelu approximate=True), fp32 out ---
  // gelu(v) = 0.5 v (1 + tanh(u)) = v / (1 + exp(-2u))
  const float* be = bias + (size_t)e * DOUT;
#pragma unroll
  for (int ni = 0; ni < 4; ++ni) {
    const int col = n0 + warp_n * 64 + ni * 16 + lp;
    const float bc = be[col];
#pragma unroll
    for (int mi = 0; mi < 8; ++mi) {
#pragma unroll
      for (int rr = 0; rr < 4; ++rr) {
        const int row = t0 + mi * 16 + q * 4 + rr;
        float v = acc[mi][ni][rr] + bc;
        const float u = 0.7978845608028654f * (v + 0.044715f * v * v * v);
        v = v / (1.0f + __expf(-2.0f * u));
        out[(size_t)row * DOUT + col] = v;
      }
    }
  }
}

extern "C" void kernel_launch(void* const* d_in, const int* in_sizes, int n_in,
                              void* d_out, int out_size, void* d_ws, size_t ws_size,
                              hipStream_t stream) {
  const float* x     = (const float*)d_in[0];
  // d_in[1] = expert_frequency: balanced by construction (512 each) -> unused
  const float* gamma = (const float*)d_in[2];
  const float* beta  = (const float*)d_in[3];
  const float* W     = (const float*)d_in[4];
  const float* bias  = (const float*)d_in[5];
  float* out = (float*)d_out;
  bf16* xn   = (bf16*)d_ws;    // 8192*1024 bf16 = 16 MiB scratch

  hipLaunchKernelGGL(ln_bf16_kernel, dim3(T_TOK), dim3(256), 0, stream,
                     x, gamma, beta, xn);
  hipLaunchKernelGGL(grouped_gemm_kernel, dim3((T_TOK / BM) * (DOUT / BN)),
                     dim3(256), 0, stream, xn, W, bias, out);
}